// Round 15
// baseline (32.948 us; speedup 1.0000x reference)
//
#include <hip/hip_runtime.h>
#include <hip/hip_bf16.h>

// Problem constants
constexpr int   D      = 512;
constexpr float ALPHA  = 1.0f;
constexpr float EPS    = 1e-9f;
constexpr float INV_CNT = 1.0f / (32.0f * 128.0f * 128.0f);  // 1/524288

// ws layout (bytes)
constexpr size_t NRM_OFF  = 0;            // 8192*512*2 = 8388608 (bf16, k-major)
constexpr size_t PART_OFF = 8388608;      // 512*4

typedef short bf16x8 __attribute__((ext_vector_type(8)));
typedef float f32x4  __attribute__((ext_vector_type(4)));

// round-to-nearest-even f32 -> bf16 bits
__device__ __forceinline__ short f2bf(float f) {
    unsigned u = __builtin_bit_cast(unsigned, f);
    unsigned r = (u + 0x7FFFu + ((u >> 16) & 1u)) >> 16;
    return (short)r;
}

// async global->LDS, 16B per lane; dest = wave-uniform base + lane*16 (HW rule)
typedef __attribute__((address_space(3))) char lds_char;
typedef const __attribute__((address_space(1))) char g_char;
__device__ __forceinline__ void glds16(const void* g, void* l) {
    __builtin_amdgcn_global_load_lds((g_char*)g, (lds_char*)l, 16, 0, 0);
}

// nrm2 layout (k-major, slot-rotated), written by k_normalize (R13/R14-verified):
//   byte(b, ks, row, slot) = ((b*16 + ks)*256 + row)*64 + slot*16
//   chunk c of row r stored at slot (c + (r>>1)) & 3

// ---------------------------------------------------------------------------
// K1: row-normalize fp32 -> bf16 into k-major rotated layout.
// (byte-identical to rounds 13/14, absmax 0)
__global__ __launch_bounds__(256) void k_normalize(const float* __restrict__ in,
                                                   short* __restrict__ nrm2) {
    const int wid  = threadIdx.x >> 6;
    const int lane = threadIdx.x & 63;
    const int r    = blockIdx.x * 4 + wid;        // global row 0..8191
    const int b    = r >> 8;
    const int row  = r & 255;
    const float4* src = (const float4*)(in + (size_t)r * D);
    float4 x0 = src[2 * lane];
    float4 x1 = src[2 * lane + 1];
    float ss = x0.x*x0.x + x0.y*x0.y + x0.z*x0.z + x0.w*x0.w
             + x1.x*x1.x + x1.y*x1.y + x1.z*x1.z + x1.w*x1.w;
    #pragma unroll
    for (int o = 32; o > 0; o >>= 1) ss += __shfl_xor(ss, o, 64);
    const float inv = rsqrtf(ss);
    bf16x8 v;                                     // elems 8*lane .. 8*lane+7
    v[0] = f2bf(x0.x * inv); v[1] = f2bf(x0.y * inv);
    v[2] = f2bf(x0.z * inv); v[3] = f2bf(x0.w * inv);
    v[4] = f2bf(x1.x * inv); v[5] = f2bf(x1.y * inv);
    v[6] = f2bf(x1.z * inv); v[7] = f2bf(x1.w * inv);
    const int ks   = lane >> 2;                   // k-slice 0..15
    const int slot = ((lane & 3) + (row >> 1)) & 3;
    char* dst = (char*)nrm2 + ((((size_t)b * 16 + ks) * 256 + row) * 64 + slot * 16);
    *(bf16x8*)dst = v;
}

// ---------------------------------------------------------------------------
// K2: FUSED gram+loss per 16-row panel. 512 blocks x 256 thr (4 waves).
// CHANGE vs R14 (single variable): gram pipeline back to TRIPLE-buffer /
// distance-2 prefetch (R13's proven pattern) -- steady-state vmcnt(10)
// keeps two 5-op groups in flight so each step's wait exposes ~0 latency,
// at the cost of 16 KB more LDS: __launch_bounds__(256,3) = 3 blocks/CU.
// Everything else byte-identical to R14 (absmax 0).
constexpr int PSTR = 260;

__global__ __launch_bounds__(256, 3) void k_fused(const short* __restrict__ nrm2,
                                                  float* __restrict__ part) {
    __shared__ __align__(16) char smem[49168];    // 3x16KB arena; P overlays; red @49152

    const int p     = blockIdx.x;
    const int slot  = p >> 3;
    const int b     = (p & 7) * 4 + (slot & 3);   // XCD-bijective: 4 batches/XCD
    const int rem   = slot >> 2;                  // 0..15
    const int chunk = rem & 7;
    const int half  = rem >> 3;
    const int w     = threadIdx.x >> 6;           // 0..3
    const int lane  = threadIdx.x & 63;
    const int fr    = lane & 15;
    const int kg    = lane >> 4;

    const char* batchbase = (const char*)nrm2 + (size_t)b * 16 * 256 * 64;

    // A: row Arow, chunk kg at rotated slot sigma = (kg + (Arow>>1))&3
    const int Arow  = half * 128 + chunk * 16 + fr;
    const int sigma = (kg + (fr >> 1)) & 3;
    const char* gA  = batchbase + Arow * 64 + sigma * 16;   // + ks*16384 per step

    // B stage: wave w's 64 rows = 4 KB contiguous within each k-slice
    const char* gBl = batchbase + w * 4096 + lane * 16;     // + ks*16384 per step
    auto stageB = [&](int ks, int bi) {
        const char* s = gBl + (size_t)ks * 16384;
        char* d = &smem[bi * 16384 + w * 4096];
        glds16(s,        d);
        glds16(s + 1024, d + 1024);
        glds16(s + 2048, d + 2048);
        glds16(s + 3072, d + 3072);
    };

    f32x4 acc0 = {0.f,0.f,0.f,0.f}, acc1 = {0.f,0.f,0.f,0.f};
    f32x4 acc2 = {0.f,0.f,0.f,0.f}, acc3 = {0.f,0.f,0.f,0.f};
    bf16x8 aA[3];                                 // rotating A buffers

    // prologue: groups 0 and 1 in flight (10 VMEM ops)
    aA[0] = *(const bf16x8*)(gA);
    stageB(0, 0);
    aA[1] = *(const bf16x8*)(gA + 16384);
    stageB(1, 1);

    // fragment read offsets (sigma pattern, R13/R14-verified banking)
    const int ro0 = ( 0 + fr) * 64 + sigma * 16;
    const int ro1 = (16 + fr) * 64 + sigma * 16;
    const int ro2 = (32 + fr) * 64 + sigma * 16;
    const int ro3 = (48 + fr) * 64 + sigma * 16;

    #pragma unroll
    for (int s = 0; s < 16; s++) {
        if (s < 14) {
            aA[(s + 2) % 3] = *(const bf16x8*)(gA + (size_t)(s + 2) * 16384);
            stageB(s + 2, (s + 2) % 3);
            asm volatile("s_waitcnt vmcnt(10)" ::: "memory");  // group s done
        } else if (s == 14) {
            asm volatile("s_waitcnt vmcnt(5)" ::: "memory");   // group 14 done
        } else {
            asm volatile("s_waitcnt vmcnt(0)" ::: "memory");   // group 15 done
        }
        __builtin_amdgcn_sched_barrier(0);
        const int bo = (s % 3) * 16384 + w * 4096;
        bf16x8 b0 = *(const bf16x8*)&smem[bo + ro0];
        bf16x8 b1 = *(const bf16x8*)&smem[bo + ro1];
        bf16x8 b2 = *(const bf16x8*)&smem[bo + ro2];
        bf16x8 b3 = *(const bf16x8*)&smem[bo + ro3];
        acc0 = __builtin_amdgcn_mfma_f32_16x16x32_bf16(aA[s % 3], b0, acc0, 0, 0, 0);
        acc1 = __builtin_amdgcn_mfma_f32_16x16x32_bf16(aA[s % 3], b1, acc1, 0, 0, 0);
        acc2 = __builtin_amdgcn_mfma_f32_16x16x32_bf16(aA[s % 3], b2, acc2, 0, 0, 0);
        acc3 = __builtin_amdgcn_mfma_f32_16x16x32_bf16(aA[s % 3], b3, acc3, 0, 0, 0);
    }

    __syncthreads();   // staging arena dead; P overlays it

    float* P   = (float*)smem;                    // 16 x PSTR f32 = 16640 B
    float* red = (float*)&smem[49152];

    // C/D layout (m89-verified): lane l, reg q -> row kg*4+q, col fr (+16j)
    {
        const int rw = kg * 4;
        const int cw = w * 64 + fr;
        #pragma unroll
        for (int q = 0; q < 4; q++) P[(rw + q) * PSTR + cw]      = acc0[q];
        #pragma unroll
        for (int q = 0; q < 4; q++) P[(rw + q) * PSTR + cw + 16] = acc1[q];
        #pragma unroll
        for (int q = 0; q < 4; q++) P[(rw + q) * PSTR + cw + 32] = acc2[q];
        #pragma unroll
        for (int q = 0; q < 4; q++) P[(rw + q) * PSTR + cw + 48] = acc3[q];
    }
    __syncthreads();

    // ---- Loss phase: 4 rows per wave, wave-private (verified rounds 3-14) --
    const int pd_off = half ? 128 : 0;
    const int pn_off = 128 - pd_off;
    float wacc = 0.f;
    #pragma unroll
    for (int rr = 0; rr < 4; rr++) {
        const int r = w * 4 + rr;
        float* prow = &P[r * PSTR];

        const float g0 = prow[pd_off + lane];
        const float g1 = prow[pd_off + lane + 64];
        float v0 = prow[pn_off + lane];
        float v1 = prow[pn_off + lane + 64];

        // bitonic sort ascending (2 elems/lane)
        #pragma unroll
        for (int kk = 2; kk <= 128; kk <<= 1) {
            if (kk == 128) {
                const float lo = fminf(v0, v1);
                const float hi = fmaxf(v0, v1);
                v0 = lo; v1 = hi;
            }
            #pragma unroll
            for (int j = (kk == 128 ? 32 : (kk >> 1)); j >= 1; j >>= 1) {
                const float p0 = __shfl_xor(v0, j, 64);
                const float p1 = __shfl_xor(v1, j, 64);
                const bool up0 = (lane & kk) == 0;
                const bool up1 = ((lane + 64) & kk) == 0;
                const bool lower = (lane & j) == 0;
                v0 = (up0 == lower) ? fminf(v0, p0) : fmaxf(v0, p0);
                v1 = (up1 == lower) ? fminf(v1, p1) : fmaxf(v1, p1);
            }
        }

        // inclusive prefix scans of the two halves
        float inc0 = v0, inc1 = v1;
        #pragma unroll
        for (int o = 1; o < 64; o <<= 1) {
            const float t0 = __shfl_up(inc0, o, 64);
            const float t1 = __shfl_up(inc1, o, 64);
            if (lane >= o) { inc0 += t0; inc1 += t1; }
        }
        const float tot0  = __shfl(inc0, 63, 64);
        const float total = tot0 + __shfl(inc1, 63, 64);

        // write sorted s[0:128] and exclusive prefix pre[0:129] in place
        prow[lane]            = v0;
        prow[64 + lane]       = v1;
        prow[130 + 1 + lane]  = inc0;
        prow[130 + 65 + lane] = tot0 + inc1;
        if (lane == 0) prow[130] = 0.f;

        // per-j: rank via guarded binary search, closed-form num/den
        #pragma unroll
        for (int h = 0; h < 2; h++) {
            const float g   = h ? g1 : g0;
            const float tau = g - 0.5f * ALPHA;   // v>0 <=> h_k > tau
            const float a   = ALPHA - 2.f * g;
            int pos = 0;
            #pragma unroll
            for (int st = 128; st > 0; st >>= 1) {
                const int nidx = pos + st;
                const float sv = prow[nidx - 1];
                pos = ((nidx <= 128) && (sv <= tau)) ? nidx : pos;
            }
            const float cnt = (float)(128 - pos);
            const float pre = prow[130 + pos];
            const float num = cnt * a + 2.f * (total - pre);
            wacc += num / (cnt + EPS);
        }
    }

    #pragma unroll
    for (int o = 32; o > 0; o >>= 1) wacc += __shfl_xor(wacc, o, 64);
    if (lane == 0) red[w] = wacc;
    __syncthreads();
    if (threadIdx.x == 0)
        part[p] = red[0] + red[1] + red[2] + red[3];
}

// ---------------------------------------------------------------------------
// K3: final reduction of 512 partials -> scalar loss. 1 block x 512.
__global__ __launch_bounds__(512) void k_reduce(const float* __restrict__ part,
                                                float* __restrict__ out) {
    __shared__ float red[8];
    const int w    = threadIdx.x >> 6;
    const int lane = threadIdx.x & 63;
    float s = part[threadIdx.x];
    #pragma unroll
    for (int o = 32; o > 0; o >>= 1) s += __shfl_xor(s, o, 64);
    if (lane == 0) red[w] = s;
    __syncthreads();
    if (threadIdx.x == 0) {
        float t = 0.f;
        #pragma unroll
        for (int i = 0; i < 8; i++) t += red[i];
        out[0] = t * INV_CNT;
    }
}

// ---------------------------------------------------------------------------
extern "C" void kernel_launch(void* const* d_in, const int* in_sizes, int n_in,
                              void* d_out, int out_size, void* d_ws, size_t ws_size,
                              hipStream_t stream) {
    const float* latent = (const float*)d_in[0];
    float* out  = (float*)d_out;
    char*  wsb  = (char*)d_ws;
    short* nrm2 = (short*)(wsb + NRM_OFF);
    float* part = (float*)(wsb + PART_OFF);

    hipLaunchKernelGGL(k_normalize, dim3(2048), dim3(256), 0, stream, latent, nrm2);
    hipLaunchKernelGGL(k_fused,     dim3(512),  dim3(256), 0, stream, nrm2, part);
    hipLaunchKernelGGL(k_reduce,    dim3(1),    dim3(512), 0, stream, part, out);
}

// Round 16
// 32.831 us; speedup vs baseline: 1.0036x; 1.0036x over previous
//
#include <hip/hip_runtime.h>
#include <hip/hip_bf16.h>

// Problem constants
constexpr int   D      = 512;
constexpr float ALPHA  = 1.0f;
constexpr float EPS    = 1e-9f;
constexpr float INV_CNT = 1.0f / (32.0f * 128.0f * 128.0f);  // 1/524288

// ws layout (bytes)
constexpr size_t NRM_OFF  = 0;            // 8192*512*2 = 8388608 (bf16, k-major)
constexpr size_t PART_OFF = 8388608;      // 512*4

typedef short bf16x8 __attribute__((ext_vector_type(8)));
typedef float f32x4  __attribute__((ext_vector_type(4)));

// round-to-nearest-even f32 -> bf16 bits
__device__ __forceinline__ short f2bf(float f) {
    unsigned u = __builtin_bit_cast(unsigned, f);
    unsigned r = (u + 0x7FFFu + ((u >> 16) & 1u)) >> 16;
    return (short)r;
}

// async global->LDS, 16B per lane; dest = wave-uniform base + lane*16 (HW rule)
typedef __attribute__((address_space(3))) char lds_char;
typedef const __attribute__((address_space(1))) char g_char;
__device__ __forceinline__ void glds16(const void* g, void* l) {
    __builtin_amdgcn_global_load_lds((g_char*)g, (lds_char*)l, 16, 0, 0);
}

// nrm2 layout (k-major, slot-rotated), written by k_normalize (R13/R14-verified):
//   byte(b, ks, row, slot) = ((b*16 + ks)*256 + row)*64 + slot*16
//   chunk c of row r stored at slot (c + (r>>1)) & 3

// ---------------------------------------------------------------------------
// K1: row-normalize fp32 -> bf16 into k-major rotated layout.
// (byte-identical to rounds 13-15, absmax 0)
__global__ __launch_bounds__(256) void k_normalize(const float* __restrict__ in,
                                                   short* __restrict__ nrm2) {
    const int wid  = threadIdx.x >> 6;
    const int lane = threadIdx.x & 63;
    const int r    = blockIdx.x * 4 + wid;        // global row 0..8191
    const int b    = r >> 8;
    const int row  = r & 255;
    const float4* src = (const float4*)(in + (size_t)r * D);
    float4 x0 = src[2 * lane];
    float4 x1 = src[2 * lane + 1];
    float ss = x0.x*x0.x + x0.y*x0.y + x0.z*x0.z + x0.w*x0.w
             + x1.x*x1.x + x1.y*x1.y + x1.z*x1.z + x1.w*x1.w;
    #pragma unroll
    for (int o = 32; o > 0; o >>= 1) ss += __shfl_xor(ss, o, 64);
    const float inv = rsqrtf(ss);
    bf16x8 v;                                     // elems 8*lane .. 8*lane+7
    v[0] = f2bf(x0.x * inv); v[1] = f2bf(x0.y * inv);
    v[2] = f2bf(x0.z * inv); v[3] = f2bf(x0.w * inv);
    v[4] = f2bf(x1.x * inv); v[5] = f2bf(x1.y * inv);
    v[6] = f2bf(x1.z * inv); v[7] = f2bf(x1.w * inv);
    const int ks   = lane >> 2;                   // k-slice 0..15
    const int slot = ((lane & 3) + (row >> 1)) & 3;
    char* dst = (char*)nrm2 + ((((size_t)b * 16 + ks) * 256 + row) * 64 + slot * 16);
    *(bf16x8*)dst = v;
}

// ---------------------------------------------------------------------------
// K2: FUSED gram+loss per 16-row panel. 512 blocks x 256 thr (4 waves),
// __launch_bounds__(256,4) -> 4 blocks/CU (R14's best-measured config:
// double-buffer / distance-1 gram pipeline).
// CHANGE vs R14 (single variable): loss-phase binary search + prefix lookup
// moved from LDS (8 dependent ds_reads ~120cy each, m117) to register-shfl
// (ds_bpermute, ~30cy) -- the sorted array and prefix sums already live in
// v0/v1/inc0/inc1 across lanes. Loss phase now has ZERO LDS writes.
// Arithmetic bit-identical (same sort/scan/closed form) -> absmax 0.
constexpr int PSTR = 260;

__global__ __launch_bounds__(256, 4) void k_fused(const short* __restrict__ nrm2,
                                                  float* __restrict__ part) {
    __shared__ __align__(16) char smem[32832];    // 2x16KB arena; P overlays; red @32768

    const int p     = blockIdx.x;
    const int slot  = p >> 3;
    const int b     = (p & 7) * 4 + (slot & 3);   // XCD-bijective: 4 batches/XCD
    const int rem   = slot >> 2;                  // 0..15
    const int chunk = rem & 7;
    const int half  = rem >> 3;
    const int w     = threadIdx.x >> 6;           // 0..3
    const int lane  = threadIdx.x & 63;
    const int fr    = lane & 15;
    const int kg    = lane >> 4;

    const char* batchbase = (const char*)nrm2 + (size_t)b * 16 * 256 * 64;

    // A: row Arow, chunk kg at rotated slot sigma = (kg + (Arow>>1))&3
    const int Arow  = half * 128 + chunk * 16 + fr;
    const int sigma = (kg + (fr >> 1)) & 3;
    const char* gA  = batchbase + Arow * 64 + sigma * 16;   // + ks*16384 per step

    // B stage: wave w's 64 rows = 4 KB contiguous within each k-slice
    const char* gBl = batchbase + w * 4096 + lane * 16;     // + ks*16384 per step
    auto stageB = [&](int ks, int bi) {
        const char* s = gBl + (size_t)ks * 16384;
        char* d = &smem[bi * 16384 + w * 4096];
        glds16(s,        d);
        glds16(s + 1024, d + 1024);
        glds16(s + 2048, d + 2048);
        glds16(s + 3072, d + 3072);
    };

    f32x4 acc0 = {0.f,0.f,0.f,0.f}, acc1 = {0.f,0.f,0.f,0.f};
    f32x4 acc2 = {0.f,0.f,0.f,0.f}, acc3 = {0.f,0.f,0.f,0.f};
    bf16x8 aA[2];

    // prologue: group 0 = [A0, B0 x4] (5 VMEM ops)
    aA[0] = *(const bf16x8*)(gA);
    stageB(0, 0);

    // fragment read offsets (sigma pattern, R13/R14-verified banking)
    const int ro0 = ( 0 + fr) * 64 + sigma * 16;
    const int ro1 = (16 + fr) * 64 + sigma * 16;
    const int ro2 = (32 + fr) * 64 + sigma * 16;
    const int ro3 = (48 + fr) * 64 + sigma * 16;

    #pragma unroll
    for (int s = 0; s < 16; s++) {
        if (s < 15) {
            aA[(s + 1) & 1] = *(const bf16x8*)(gA + (size_t)(s + 1) * 16384);
            stageB(s + 1, (s + 1) & 1);
            asm volatile("s_waitcnt vmcnt(5)" ::: "memory");   // group s done
        } else {
            asm volatile("s_waitcnt vmcnt(0)" ::: "memory");
        }
        __builtin_amdgcn_sched_barrier(0);
        const int bo = (s & 1) * 16384 + w * 4096;
        bf16x8 b0 = *(const bf16x8*)&smem[bo + ro0];
        bf16x8 b1 = *(const bf16x8*)&smem[bo + ro1];
        bf16x8 b2 = *(const bf16x8*)&smem[bo + ro2];
        bf16x8 b3 = *(const bf16x8*)&smem[bo + ro3];
        acc0 = __builtin_amdgcn_mfma_f32_16x16x32_bf16(aA[s & 1], b0, acc0, 0, 0, 0);
        acc1 = __builtin_amdgcn_mfma_f32_16x16x32_bf16(aA[s & 1], b1, acc1, 0, 0, 0);
        acc2 = __builtin_amdgcn_mfma_f32_16x16x32_bf16(aA[s & 1], b2, acc2, 0, 0, 0);
        acc3 = __builtin_amdgcn_mfma_f32_16x16x32_bf16(aA[s & 1], b3, acc3, 0, 0, 0);
    }

    __syncthreads();   // staging arena dead; P overlays it

    float* P   = (float*)smem;                    // 16 x PSTR f32 = 16640 B
    float* red = (float*)&smem[32768];

    // C/D layout (m89-verified): lane l, reg q -> row kg*4+q, col fr (+16j)
    {
        const int rw = kg * 4;
        const int cw = w * 64 + fr;
        #pragma unroll
        for (int q = 0; q < 4; q++) P[(rw + q) * PSTR + cw]      = acc0[q];
        #pragma unroll
        for (int q = 0; q < 4; q++) P[(rw + q) * PSTR + cw + 16] = acc1[q];
        #pragma unroll
        for (int q = 0; q < 4; q++) P[(rw + q) * PSTR + cw + 32] = acc2[q];
        #pragma unroll
        for (int q = 0; q < 4; q++) P[(rw + q) * PSTR + cw + 48] = acc3[q];
    }
    __syncthreads();

    // ---- Loss phase: 4 rows per wave; all lookups in-register via shfl ----
    const int pd_off = half ? 128 : 0;
    const int pn_off = 128 - pd_off;
    float wacc = 0.f;
    #pragma unroll
    for (int rr = 0; rr < 4; rr++) {
        const int r = w * 4 + rr;
        const float* prow = &P[r * PSTR];

        const float g0 = prow[pd_off + lane];
        const float g1 = prow[pd_off + lane + 64];
        float v0 = prow[pn_off + lane];
        float v1 = prow[pn_off + lane + 64];

        // bitonic sort ascending (2 elems/lane) -- unchanged
        #pragma unroll
        for (int kk = 2; kk <= 128; kk <<= 1) {
            if (kk == 128) {
                const float lo = fminf(v0, v1);
                const float hi = fmaxf(v0, v1);
                v0 = lo; v1 = hi;
            }
            #pragma unroll
            for (int j = (kk == 128 ? 32 : (kk >> 1)); j >= 1; j >>= 1) {
                const float p0 = __shfl_xor(v0, j, 64);
                const float p1 = __shfl_xor(v1, j, 64);
                const bool up0 = (lane & kk) == 0;
                const bool up1 = ((lane + 64) & kk) == 0;
                const bool lower = (lane & j) == 0;
                v0 = (up0 == lower) ? fminf(v0, p0) : fmaxf(v0, p0);
                v1 = (up1 == lower) ? fminf(v1, p1) : fmaxf(v1, p1);
            }
        }

        // inclusive prefix scans of the two halves -- unchanged
        float inc0 = v0, inc1 = v1;
        #pragma unroll
        for (int o = 1; o < 64; o <<= 1) {
            const float t0 = __shfl_up(inc0, o, 64);
            const float t1 = __shfl_up(inc1, o, 64);
            if (lane >= o) { inc0 += t0; inc1 += t1; }
        }
        const float tot0  = __shfl(inc0, 63, 64);
        const float total = tot0 + __shfl(inc1, 63, 64);

        // per-j: rank via register-shfl binary search (no LDS round-trip).
        // sorted s[i]: i<64 -> v0@lane i ; i>=64 -> v1@lane i-64
        // pre[n] (exclusive): n==0 -> 0 ; n<=64 -> inc0@lane n-1 ;
        //                     n>64 -> tot0 + inc1@lane n-65
        #pragma unroll
        for (int h = 0; h < 2; h++) {
            const float g   = h ? g1 : g0;
            const float tau = g - 0.5f * ALPHA;   // v>0 <=> h_k > tau
            const float a   = ALPHA - 2.f * g;
            int pos = 0;                          // rank = #{s_k <= tau}
            #pragma unroll
            for (int st = 128; st > 0; st >>= 1) {
                const int nidx = pos + st;
                const int si   = nidx - 1;        // 0..127 when valid
                const float s0 = __shfl(v0, si & 63, 64);
                const float s1 = __shfl(v1, si & 63, 64);
                const float sv = (si < 64) ? s0 : s1;
                pos = ((nidx <= 128) && (sv <= tau)) ? nidx : pos;
            }
            const float p0 = __shfl(inc0, (pos - 1) & 63, 64);
            const float p1 = __shfl(inc1, (pos - 65) & 63, 64);
            const float pre = (pos == 0) ? 0.f : ((pos <= 64) ? p0 : tot0 + p1);
            const float cnt = (float)(128 - pos);
            const float num = cnt * a + 2.f * (total - pre);
            wacc += num / (cnt + EPS);
        }
    }

    #pragma unroll
    for (int o = 32; o > 0; o >>= 1) wacc += __shfl_xor(wacc, o, 64);
    if (lane == 0) red[w] = wacc;
    __syncthreads();
    if (threadIdx.x == 0)
        part[p] = red[0] + red[1] + red[2] + red[3];
}

// ---------------------------------------------------------------------------
// K3: final reduction of 512 partials -> scalar loss. 1 block x 512.
__global__ __launch_bounds__(512) void k_reduce(const float* __restrict__ part,
                                                float* __restrict__ out) {
    __shared__ float red[8];
    const int w    = threadIdx.x >> 6;
    const int lane = threadIdx.x & 63;
    float s = part[threadIdx.x];
    #pragma unroll
    for (int o = 32; o > 0; o >>= 1) s += __shfl_xor(s, o, 64);
    if (lane == 0) red[w] = s;
    __syncthreads();
    if (threadIdx.x == 0) {
        float t = 0.f;
        #pragma unroll
        for (int i = 0; i < 8; i++) t += red[i];
        out[0] = t * INV_CNT;
    }
}

// ---------------------------------------------------------------------------
extern "C" void kernel_launch(void* const* d_in, const int* in_sizes, int n_in,
                              void* d_out, int out_size, void* d_ws, size_t ws_size,
                              hipStream_t stream) {
    const float* latent = (const float*)d_in[0];
    float* out  = (float*)d_out;
    char*  wsb  = (char*)d_ws;
    short* nrm2 = (short*)(wsb + NRM_OFF);
    float* part = (float*)(wsb + PART_OFF);

    hipLaunchKernelGGL(k_normalize, dim3(2048), dim3(256), 0, stream, latent, nrm2);
    hipLaunchKernelGGL(k_fused,     dim3(512),  dim3(256), 0, stream, nrm2, part);
    hipLaunchKernelGGL(k_reduce,    dim3(1),    dim3(512), 0, stream, part, out);
}

// Round 17
// 30.330 us; speedup vs baseline: 1.0863x; 1.0825x over previous
//
#include <hip/hip_runtime.h>
#include <hip/hip_bf16.h>

// Problem constants
constexpr int   D      = 512;
constexpr float ALPHA  = 1.0f;
constexpr float EPS    = 1e-9f;
constexpr float INV_CNT = 1.0f / (32.0f * 128.0f * 128.0f);  // 1/524288

// ws layout (bytes)
constexpr size_t NRM_OFF  = 0;            // 8192*512*2 = 8388608 (bf16, k-major)
constexpr size_t PART_OFF = 8388608;      // 512*4

typedef short bf16x8 __attribute__((ext_vector_type(8)));
typedef float f32x4  __attribute__((ext_vector_type(4)));

// round-to-nearest-even f32 -> bf16 bits
__device__ __forceinline__ short f2bf(float f) {
    unsigned u = __builtin_bit_cast(unsigned, f);
    unsigned r = (u + 0x7FFFu + ((u >> 16) & 1u)) >> 16;
    return (short)r;
}

// async global->LDS, 16B per lane; dest = wave-uniform base + lane*16 (HW rule)
typedef __attribute__((address_space(3))) char lds_char;
typedef const __attribute__((address_space(1))) char g_char;
__device__ __forceinline__ void glds16(const void* g, void* l) {
    __builtin_amdgcn_global_load_lds((g_char*)g, (lds_char*)l, 16, 0, 0);
}

// nrm2 layout (k-major, slot-rotated), written by k_normalize:
//   byte(b, ks, row, slot) = ((b*16 + ks)*256 + row)*64 + slot*16
//   chunk c of row r stored at slot (c + (r>>1)) & 3

// ---------------------------------------------------------------------------
// K1: row-normalize fp32 -> bf16 into k-major rotated layout.
// CHANGE vs R14 (single variable): XCD-co-located row assignment.
// Block p (on XCD p&7 under round-robin dispatch) writes rows
//   (p&7)*1024 + (p>>3)*4 .. +4   (bijective over 8192 rows)
// so batch b's entire nrm2 region is PRODUCED on XCD b>>2 -- the same XCD
// that k_fused's swizzle assigns as its CONSUMER. Gram staging reads become
// same-XCD (local L2 / local L3 slice) instead of cross-fabric first touches.
__global__ __launch_bounds__(256) void k_normalize(const float* __restrict__ in,
                                                   short* __restrict__ nrm2) {
    const int wid  = threadIdx.x >> 6;
    const int lane = threadIdx.x & 63;
    const int p    = blockIdx.x;
    const int r    = (p & 7) * 1024 + (p >> 3) * 4 + wid;   // global row 0..8191
    const int b    = r >> 8;
    const int row  = r & 255;
    const float4* src = (const float4*)(in + (size_t)r * D);
    float4 x0 = src[2 * lane];
    float4 x1 = src[2 * lane + 1];
    float ss = x0.x*x0.x + x0.y*x0.y + x0.z*x0.z + x0.w*x0.w
             + x1.x*x1.x + x1.y*x1.y + x1.z*x1.z + x1.w*x1.w;
    #pragma unroll
    for (int o = 32; o > 0; o >>= 1) ss += __shfl_xor(ss, o, 64);
    const float inv = rsqrtf(ss);
    bf16x8 v;                                     // elems 8*lane .. 8*lane+7
    v[0] = f2bf(x0.x * inv); v[1] = f2bf(x0.y * inv);
    v[2] = f2bf(x0.z * inv); v[3] = f2bf(x0.w * inv);
    v[4] = f2bf(x1.x * inv); v[5] = f2bf(x1.y * inv);
    v[6] = f2bf(x1.z * inv); v[7] = f2bf(x1.w * inv);
    const int ks   = lane >> 2;                   // k-slice 0..15
    const int slot = ((lane & 3) + (row >> 1)) & 3;
    char* dst = (char*)nrm2 + ((((size_t)b * 16 + ks) * 256 + row) * 64 + slot * 16);
    *(bf16x8*)dst = v;
}

// ---------------------------------------------------------------------------
// K2: FUSED gram+loss per 16-row panel. 512 blocks x 256 thr (4 waves).
// (byte-identical to round 14, the best-measured config: double-buffer /
// distance-1 gram pipeline, LDS binary-search loss; absmax 0)
constexpr int PSTR = 260;

__global__ __launch_bounds__(256, 4) void k_fused(const short* __restrict__ nrm2,
                                                  float* __restrict__ part) {
    __shared__ __align__(16) char smem[32832];    // 2x16KB arena; P overlays; red @32768

    const int p     = blockIdx.x;
    const int slot  = p >> 3;
    const int b     = (p & 7) * 4 + (slot & 3);   // XCD-bijective: 4 batches/XCD
    const int rem   = slot >> 2;                  // 0..15
    const int chunk = rem & 7;
    const int half  = rem >> 3;
    const int w     = threadIdx.x >> 6;           // 0..3
    const int lane  = threadIdx.x & 63;
    const int fr    = lane & 15;
    const int kg    = lane >> 4;

    const char* batchbase = (const char*)nrm2 + (size_t)b * 16 * 256 * 64;

    // A: row Arow, chunk kg at rotated slot sigma = (kg + (Arow>>1))&3
    const int Arow  = half * 128 + chunk * 16 + fr;
    const int sigma = (kg + (fr >> 1)) & 3;
    const char* gA  = batchbase + Arow * 64 + sigma * 16;   // + ks*16384 per step

    // B stage: wave w's 64 rows = 4 KB contiguous within each k-slice
    const char* gBl = batchbase + w * 4096 + lane * 16;     // + ks*16384 per step
    auto stageB = [&](int ks, int bi) {
        const char* s = gBl + (size_t)ks * 16384;
        char* d = &smem[bi * 16384 + w * 4096];
        glds16(s,        d);
        glds16(s + 1024, d + 1024);
        glds16(s + 2048, d + 2048);
        glds16(s + 3072, d + 3072);
    };

    f32x4 acc0 = {0.f,0.f,0.f,0.f}, acc1 = {0.f,0.f,0.f,0.f};
    f32x4 acc2 = {0.f,0.f,0.f,0.f}, acc3 = {0.f,0.f,0.f,0.f};
    bf16x8 aA[2];

    // prologue: group 0 = [A0, B0 x4] (5 VMEM ops)
    aA[0] = *(const bf16x8*)(gA);
    stageB(0, 0);

    // fragment read offsets (sigma pattern, R13/R14-verified banking)
    const int ro0 = ( 0 + fr) * 64 + sigma * 16;
    const int ro1 = (16 + fr) * 64 + sigma * 16;
    const int ro2 = (32 + fr) * 64 + sigma * 16;
    const int ro3 = (48 + fr) * 64 + sigma * 16;

    #pragma unroll
    for (int s = 0; s < 16; s++) {
        if (s < 15) {
            aA[(s + 1) & 1] = *(const bf16x8*)(gA + (size_t)(s + 1) * 16384);
            stageB(s + 1, (s + 1) & 1);
            asm volatile("s_waitcnt vmcnt(5)" ::: "memory");   // group s done
        } else {
            asm volatile("s_waitcnt vmcnt(0)" ::: "memory");
        }
        __builtin_amdgcn_sched_barrier(0);
        const int bo = (s & 1) * 16384 + w * 4096;
        bf16x8 b0 = *(const bf16x8*)&smem[bo + ro0];
        bf16x8 b1 = *(const bf16x8*)&smem[bo + ro1];
        bf16x8 b2 = *(const bf16x8*)&smem[bo + ro2];
        bf16x8 b3 = *(const bf16x8*)&smem[bo + ro3];
        acc0 = __builtin_amdgcn_mfma_f32_16x16x32_bf16(aA[s & 1], b0, acc0, 0, 0, 0);
        acc1 = __builtin_amdgcn_mfma_f32_16x16x32_bf16(aA[s & 1], b1, acc1, 0, 0, 0);
        acc2 = __builtin_amdgcn_mfma_f32_16x16x32_bf16(aA[s & 1], b2, acc2, 0, 0, 0);
        acc3 = __builtin_amdgcn_mfma_f32_16x16x32_bf16(aA[s & 1], b3, acc3, 0, 0, 0);
    }

    __syncthreads();   // staging arena dead; P overlays it

    float* P   = (float*)smem;                    // 16 x PSTR f32 = 16640 B
    float* red = (float*)&smem[32768];

    // C/D layout (m89-verified): lane l, reg q -> row kg*4+q, col fr (+16j)
    {
        const int rw = kg * 4;
        const int cw = w * 64 + fr;
        #pragma unroll
        for (int q = 0; q < 4; q++) P[(rw + q) * PSTR + cw]      = acc0[q];
        #pragma unroll
        for (int q = 0; q < 4; q++) P[(rw + q) * PSTR + cw + 16] = acc1[q];
        #pragma unroll
        for (int q = 0; q < 4; q++) P[(rw + q) * PSTR + cw + 32] = acc2[q];
        #pragma unroll
        for (int q = 0; q < 4; q++) P[(rw + q) * PSTR + cw + 48] = acc3[q];
    }
    __syncthreads();

    // ---- Loss phase: 4 rows per wave, wave-private (verified rounds 3-16) --
    const int pd_off = half ? 128 : 0;
    const int pn_off = 128 - pd_off;
    float wacc = 0.f;
    #pragma unroll
    for (int rr = 0; rr < 4; rr++) {
        const int r = w * 4 + rr;
        float* prow = &P[r * PSTR];

        const float g0 = prow[pd_off + lane];
        const float g1 = prow[pd_off + lane + 64];
        float v0 = prow[pn_off + lane];
        float v1 = prow[pn_off + lane + 64];

        // bitonic sort ascending (2 elems/lane)
        #pragma unroll
        for (int kk = 2; kk <= 128; kk <<= 1) {
            if (kk == 128) {
                const float lo = fminf(v0, v1);
                const float hi = fmaxf(v0, v1);
                v0 = lo; v1 = hi;
            }
            #pragma unroll
            for (int j = (kk == 128 ? 32 : (kk >> 1)); j >= 1; j >>= 1) {
                const float p0 = __shfl_xor(v0, j, 64);
                const float p1 = __shfl_xor(v1, j, 64);
                const bool up0 = (lane & kk) == 0;
                const bool up1 = ((lane + 64) & kk) == 0;
                const bool lower = (lane & j) == 0;
                v0 = (up0 == lower) ? fminf(v0, p0) : fmaxf(v0, p0);
                v1 = (up1 == lower) ? fminf(v1, p1) : fmaxf(v1, p1);
            }
        }

        // inclusive prefix scans of the two halves
        float inc0 = v0, inc1 = v1;
        #pragma unroll
        for (int o = 1; o < 64; o <<= 1) {
            const float t0 = __shfl_up(inc0, o, 64);
            const float t1 = __shfl_up(inc1, o, 64);
            if (lane >= o) { inc0 += t0; inc1 += t1; }
        }
        const float tot0  = __shfl(inc0, 63, 64);
        const float total = tot0 + __shfl(inc1, 63, 64);

        // write sorted s[0:128] and exclusive prefix pre[0:129] in place
        prow[lane]            = v0;
        prow[64 + lane]       = v1;
        prow[130 + 1 + lane]  = inc0;
        prow[130 + 65 + lane] = tot0 + inc1;
        if (lane == 0) prow[130] = 0.f;

        // per-j: rank via guarded binary search, closed-form num/den
        #pragma unroll
        for (int h = 0; h < 2; h++) {
            const float g   = h ? g1 : g0;
            const float tau = g - 0.5f * ALPHA;   // v>0 <=> h_k > tau
            const float a   = ALPHA - 2.f * g;
            int pos = 0;
            #pragma unroll
            for (int st = 128; st > 0; st >>= 1) {
                const int nidx = pos + st;
                const float sv = prow[nidx - 1];
                pos = ((nidx <= 128) && (sv <= tau)) ? nidx : pos;
            }
            const float cnt = (float)(128 - pos);
            const float pre = prow[130 + pos];
            const float num = cnt * a + 2.f * (total - pre);
            wacc += num / (cnt + EPS);
        }
    }

    #pragma unroll
    for (int o = 32; o > 0; o >>= 1) wacc += __shfl_xor(wacc, o, 64);
    if (lane == 0) red[w] = wacc;
    __syncthreads();
    if (threadIdx.x == 0)
        part[p] = red[0] + red[1] + red[2] + red[3];
}

// ---------------------------------------------------------------------------
// K3: final reduction of 512 partials -> scalar loss. 1 block x 512.
__global__ __launch_bounds__(512) void k_reduce(const float* __restrict__ part,
                                                float* __restrict__ out) {
    __shared__ float red[8];
    const int w    = threadIdx.x >> 6;
    const int lane = threadIdx.x & 63;
    float s = part[threadIdx.x];
    #pragma unroll
    for (int o = 32; o > 0; o >>= 1) s += __shfl_xor(s, o, 64);
    if (lane == 0) red[w] = s;
    __syncthreads();
    if (threadIdx.x == 0) {
        float t = 0.f;
        #pragma unroll
        for (int i = 0; i < 8; i++) t += red[i];
        out[0] = t * INV_CNT;
    }
}

// ---------------------------------------------------------------------------
extern "C" void kernel_launch(void* const* d_in, const int* in_sizes, int n_in,
                              void* d_out, int out_size, void* d_ws, size_t ws_size,
                              hipStream_t stream) {
    const float* latent = (const float*)d_in[0];
    float* out  = (float*)d_out;
    char*  wsb  = (char*)d_ws;
    short* nrm2 = (short*)(wsb + NRM_OFF);
    float* part = (float*)(wsb + PART_OFF);

    hipLaunchKernelGGL(k_normalize, dim3(2048), dim3(256), 0, stream, latent, nrm2);
    hipLaunchKernelGGL(k_fused,     dim3(512),  dim3(256), 0, stream, nrm2, part);
    hipLaunchKernelGGL(k_reduce,    dim3(1),    dim3(512), 0, stream, part, out);
}